// Round 11
// baseline (176.753 us; speedup 1.0000x reference)
//
#include <hip/hip_runtime.h>
#include <math.h>

#define B 64
#define D 256
#define M 8000
#define N 32
#define LG_LD 8000
#define EPB 16          // entries per block (flash k_heavy)
#define NBLK (M / EPB)  // 500

typedef unsigned short u16;
typedef __bf16 bf16x8 __attribute__((ext_vector_type(8)));
typedef float fx4 __attribute__((ext_vector_type(4)));

#define STR_E  264   // u16 stride of sE rows (n-major)
#define STR_P  40    // u16 stride of sP rows (b-major)
// sET interleaved layout: u16 idx of (d, slot) = (d>>2)*136 + (slot>>3)*32 + (d&3)*8 + (slot&7)
// entry-phase slot = sigma(n) = 4*(n&7) + (n>>3); key-phase slot2(m) = 2*(m&7) + (m>>3)

static __device__ __forceinline__ u16 f2bf(float x) {
    unsigned int u = __float_as_uint(x);
    u += 0x7FFFu + ((u >> 16) & 1u);
    return (u16)(u >> 16);
}
static __device__ __forceinline__ float bf2f(u16 h) {
    return __uint_as_float(((unsigned)h) << 16);
}
static __device__ __forceinline__ uint4 pack8(float4 va, float4 vb, float msk) {
    unsigned p0 = (unsigned)f2bf(va.x * msk) | ((unsigned)f2bf(va.y * msk) << 16);
    unsigned p1 = (unsigned)f2bf(va.z * msk) | ((unsigned)f2bf(va.w * msk) << 16);
    unsigned p2 = (unsigned)f2bf(vb.x * msk) | ((unsigned)f2bf(vb.y * msk) << 16);
    unsigned p3 = (unsigned)f2bf(vb.z * msk) | ((unsigned)f2bf(vb.w * msk) << 16);
    return make_uint4(p0, p1, p2, p3);
}

// ---- k_prep2: keb gather (0..999) + qbf conv (1000..1007) + vq proj (1008..1071)
__global__ __launch_bounds__(256) void k_prep2(const int* __restrict__ keys,
                                               const float* __restrict__ emb,
                                               const float* __restrict__ q,
                                               const float* __restrict__ W,
                                               const float* __restrict__ bias,
                                               u16* __restrict__ qbf,
                                               u16* __restrict__ keb,
                                               u16* __restrict__ vqb) {
    __shared__ float qs[D];
    int t = threadIdx.x, bid = blockIdx.x;
    if (bid < 1000) {
        int c = bid * 256 + t;   // 8000*32 chunks of 8 elems
        int j = c >> 5, sp = c & 31;
        int id = keys[j];
        const float* rp = emb + (size_t)id * D + sp * 8;
        float4 v0 = *(const float4*)rp;
        float4 v1 = *(const float4*)(rp + 4);
        float msk = (id != 0) ? 1.f : 0.f;
        uint4 pk = pack8(v0, v1, msk);
        *(uint4*)(keb + (size_t)j * D + sp * 8) = pk;
    } else if (bid < 1008) {
        size_t idx = (size_t)(bid - 1000) * 2048 + (size_t)t * 8;
        float4 v0 = *(const float4*)(q + idx);
        float4 v1 = *(const float4*)(q + idx + 4);
        uint4 pk = pack8(v0, v1, 1.f);
        *(uint4*)(qbf + idx) = pk;
    } else {
        int b = bid - 1008;
        qs[t] = q[b * D + t];
        __syncthreads();
        const float* wr = W + t * D;
        float acc = bias[t];
#pragma unroll 8
        for (int k = 0; k < D; k += 4) {
            float4 w4 = *(const float4*)(wr + k);
            acc += qs[k] * w4.x + qs[k + 1] * w4.y + qs[k + 2] * w4.z + qs[k + 3] * w4.w;
        }
        vqb[b * D + t] = f2bf(acc);
    }
}

// ---- k_heavy_f: fused logits + flash stats + per-entry value attention + numK mini-PV.
//      fp32 gather straight from wordemb; bf16 convert+mask fused into staging.
//      2-entry-deep gather pipeline: even entries in pf[0], odd in pf[1]; entry loop
//      fully unrolled so all pf/id indices are compile-time (no scratch).
__global__ __launch_bounds__(256, 2) void k_heavy_f(const int* __restrict__ entries,
                                                    const float* __restrict__ emb,
                                                    const u16* __restrict__ vqb,
                                                    const u16* __restrict__ qbf,
                                                    const u16* __restrict__ keb,
                                                    float* __restrict__ lg,
                                                    u16* __restrict__ numCp,
                                                    u16* __restrict__ numKp,
                                                    float* __restrict__ mLp,
                                                    float* __restrict__ denLp) {
    __shared__ __align__(16) u16 sEu[2][N * STR_E];   // 33,792 B
    __shared__ __align__(16) u16 sETu[2][64 * 136];   // 34,816 B
    __shared__ __align__(16) u16 sPu[B * STR_P];      //  5,120 B
    __shared__ float sw[EPB][B];                      //  4,096 B

    int t = threadIdx.x;
    int lane = t & 63, l = lane & 15, q = lane >> 4, w = t >> 6;
    int b0 = 16 * w;
    int sp = t & 31, n0 = t >> 5;
    int m0 = blockIdx.x * EPB;
    int bb = t & 63, y = t >> 6;

    // ---- earliest: ids(e0) + fp32 gather(e0) — flies underneath the fused logits ----
    int id2[2][4], idn[4];
    float4 pf[2][8];   // two sets: 4 rows x 2 float4 each
#pragma unroll
    for (int i = 0; i < 4; ++i) id2[0][i] = entries[m0 * N + n0 + 8 * i];
#pragma unroll
    for (int i = 0; i < 4; ++i) {
        const float* rp = emb + (size_t)id2[0][i] * D + sp * 8;
        pf[0][2 * i]     = *(const float4*)rp;
        pf[0][2 * i + 1] = *(const float4*)(rp + 4);
    }

    // ---- fused logits: aL[r] = lg[b0+4q+r][m0+l]  (16 m x 64 b tile) ----
    fx4 zero4 = {0.f, 0.f, 0.f, 0.f};
    fx4 aL = zero4;
#pragma unroll
    for (int s = 0; s < 8; ++s) {
        bf16x8 a  = *(const bf16x8*)(qbf + (size_t)(b0 + l) * D + 32 * s + 8 * q);
        bf16x8 bq = *(const bf16x8*)(keb + (size_t)(m0 + l) * D + 32 * s + 8 * q);
        aL = __builtin_amdgcn_mfma_f32_16x16x32_bf16(a, bq, aL, 0, 0, 0);
    }
#pragma unroll
    for (int r = 0; r < 4; ++r)
        lg[(size_t)(b0 + 4 * q + r) * LG_LD + m0 + l] = aL[r];

    // ---- flash stats via 16-lane shuffles: mL[b], weights sw[m][b], den[b] ----
#pragma unroll
    for (int r = 0; r < 4; ++r) {
        float m_ = aL[r];
        m_ = fmaxf(m_, __shfl_xor(m_, 1));
        m_ = fmaxf(m_, __shfl_xor(m_, 2));
        m_ = fmaxf(m_, __shfl_xor(m_, 4));
        m_ = fmaxf(m_, __shfl_xor(m_, 8));
        float wv = __expf(aL[r] - m_);
        sw[l][b0 + 4 * q + r] = wv;     // entry m0+l, batch b0+4q+r (wave-private columns)
        float d_ = wv;
        d_ += __shfl_xor(d_, 1);
        d_ += __shfl_xor(d_, 2);
        d_ += __shfl_xor(d_, 4);
        d_ += __shfl_xor(d_, 8);
        if (l == 0) {
            mLp[blockIdx.x * B + b0 + 4 * q + r] = m_;
            denLp[blockIdx.x * B + b0 + 4 * q + r] = d_;
        }
    }

    // persistent vq B-fragments
    bf16x8 vqf[8];
#pragma unroll
    for (int s = 0; s < 8; ++s)
        vqf[s] = *(const bf16x8*)(vqb + (b0 + l) * D + 32 * s + 8 * q);

    fx4 acc[16];
#pragma unroll
    for (int dt = 0; dt < 16; ++dt) acc[dt] = zero4;

    // ---- stage e0 into buf0 (convert+mask) ----
    {
        uint4 pk[4];
#pragma unroll
        for (int i = 0; i < 4; ++i) {
            float msk = (id2[0][i] != 0) ? 1.f : 0.f;
            pk[i] = pack8(pf[0][2 * i], pf[0][2 * i + 1], msk);
            *(uint4*)&sEu[0][(n0 + 8 * i) * STR_E + sp * 8] = pk[i];
        }
#pragma unroll
        for (int j = 0; j < 8; ++j) {
            unsigned a0 = (((unsigned*)&pk[0])[j >> 1] >> ((j & 1) * 16)) & 0xFFFFu;
            unsigned a1 = (((unsigned*)&pk[1])[j >> 1] >> ((j & 1) * 16)) & 0xFFFFu;
            unsigned a2 = (((unsigned*)&pk[2])[j >> 1] >> ((j & 1) * 16)) & 0xFFFFu;
            unsigned a3 = (((unsigned*)&pk[3])[j >> 1] >> ((j & 1) * 16)) & 0xFFFFu;
            uint2 pr = make_uint2(a0 | (a1 << 16), a2 | (a3 << 16));
            int off = (2 * sp + (j >> 2)) * 136 + (n0 >> 1) * 32 + (j & 3) * 8 + (n0 & 1) * 4;
            *(uint2*)&sETu[0][off] = pr;
        }
    }
    // ---- gather e1 into pf[0], e2 into pf[1]; idn <- ids(e3) ----
#pragma unroll
    for (int i = 0; i < 4; ++i) id2[0][i] = entries[(m0 + 1) * N + n0 + 8 * i];
#pragma unroll
    for (int i = 0; i < 4; ++i) {
        const float* rp = emb + (size_t)id2[0][i] * D + sp * 8;
        pf[0][2 * i]     = *(const float4*)rp;
        pf[0][2 * i + 1] = *(const float4*)(rp + 4);
    }
#pragma unroll
    for (int i = 0; i < 4; ++i) id2[1][i] = entries[(m0 + 2) * N + n0 + 8 * i];
#pragma unroll
    for (int i = 0; i < 4; ++i) {
        const float* rp = emb + (size_t)id2[1][i] * D + sp * 8;
        pf[1][2 * i]     = *(const float4*)rp;
        pf[1][2 * i + 1] = *(const float4*)(rp + 4);
    }
#pragma unroll
    for (int i = 0; i < 4; ++i) idn[i] = entries[(m0 + 3) * N + n0 + 8 * i];

    int offL = (l >> 2) * 136 + (l & 3) * 8;

    // ---- entry loop (FULLY unrolled): [bar] stage(e+1 from pf[e&1]) ->
    //      gather(e+3 into pf[e&1]) -> compute(e from buf[e&1]) ----
#pragma unroll
    for (int e = 0; e < EPB; ++e) {
        __syncthreads();   // buf[e&1] staged; prev reads of buf[(e+1)&1] done
        const int s2 = e & 1;          // pf set holding entry e+1 (constant after unroll)
        const int nxt = (e + 1) & 1;   // LDS buf for entry e+1
        if (e < EPB - 1) {
            // (a) stage entry e+1 from pf[s2]: convert+mask, write sE (b128) + sET (b64)
            uint4 pk[4];
#pragma unroll
            for (int i = 0; i < 4; ++i) {
                float msk = (id2[s2][i] != 0) ? 1.f : 0.f;
                pk[i] = pack8(pf[s2][2 * i], pf[s2][2 * i + 1], msk);
                *(uint4*)&sEu[nxt][(n0 + 8 * i) * STR_E + sp * 8] = pk[i];
            }
#pragma unroll
            for (int j = 0; j < 8; ++j) {
                unsigned a0 = (((unsigned*)&pk[0])[j >> 1] >> ((j & 1) * 16)) & 0xFFFFu;
                unsigned a1 = (((unsigned*)&pk[1])[j >> 1] >> ((j & 1) * 16)) & 0xFFFFu;
                unsigned a2 = (((unsigned*)&pk[2])[j >> 1] >> ((j & 1) * 16)) & 0xFFFFu;
                unsigned a3 = (((unsigned*)&pk[3])[j >> 1] >> ((j & 1) * 16)) & 0xFFFFu;
                uint2 pr = make_uint2(a0 | (a1 << 16), a2 | (a3 << 16));
                int off = (2 * sp + (j >> 2)) * 136 + (n0 >> 1) * 32 + (j & 3) * 8 + (n0 & 1) * 4;
                *(uint2*)&sETu[nxt][off] = pr;
            }
            // (b) issue fp32 gather of entry e+3 into pf[s2] (consumed at iter e+2:
            //     two compute phases + two barriers of latency coverage)
            if (e + 3 < EPB) {
#pragma unroll
                for (int i = 0; i < 4; ++i) id2[s2][i] = idn[i];
#pragma unroll
                for (int i = 0; i < 4; ++i) {
                    const float* rp = emb + (size_t)idn[i] * D + sp * 8;
                    pf[s2][2 * i]     = *(const float4*)rp;
                    pf[s2][2 * i + 1] = *(const float4*)(rp + 4);
                }
                if (e + 4 < EPB) {
#pragma unroll
                    for (int i = 0; i < 4; ++i) idn[i] = entries[(m0 + e + 4) * N + n0 + 8 * i];
                }
            }
        }
        // (c) compute entry e from buf[e&1]
        fx4 accS[2];
        accS[0] = zero4; accS[1] = zero4;
#pragma unroll
        for (int T = 0; T < 2; ++T)
#pragma unroll
            for (int s = 0; s < 8; ++s) {
                bf16x8 ea = *(const bf16x8*)&sEu[s2][(16 * T + l) * STR_E + 32 * s + 8 * q];
                accS[T] = __builtin_amdgcn_mfma_f32_16x16x32_bf16(ea, vqf[s], accS[T], 0, 0, 0);
            }
        float swb = sw[e][b0 + l];
        float mx = -INFINITY;
#pragma unroll
        for (int T = 0; T < 2; ++T)
#pragma unroll
            for (int r = 0; r < 4; ++r) mx = fmaxf(mx, accS[T][r]);
        mx = fmaxf(mx, __shfl_xor(mx, 16));
        mx = fmaxf(mx, __shfl_xor(mx, 32));
        float pe[2][4], sum = 0.f;
#pragma unroll
        for (int T = 0; T < 2; ++T)
#pragma unroll
            for (int r = 0; r < 4; ++r) {
                pe[T][r] = __expf(accS[T][r] - mx);
                sum += pe[T][r];
            }
        sum += __shfl_xor(sum, 16);
        sum += __shfl_xor(sum, 32);
        float sc = swb / sum;
#pragma unroll
        for (int T = 0; T < 2; ++T)
#pragma unroll
            for (int r = 0; r < 4; ++r) {
                int nn = 16 * T + 4 * q + r;
                int slot = 4 * (nn & 7) + (nn >> 3);
                sPu[(b0 + l) * STR_P + slot] = f2bf(pe[T][r] * sc);
            }
        bf16x8 pa = *(const bf16x8*)&sPu[(b0 + l) * STR_P + 8 * q];
#pragma unroll
        for (int dt = 0; dt < 16; ++dt) {
            bf16x8 eb = *(const bf16x8*)&sETu[s2][offL + dt * 544 + q * 32];
            acc[dt] = __builtin_amdgcn_mfma_f32_16x16x32_bf16(pa, eb, acc[dt], 0, 0, 0);
        }
    }

    // ---- store numC partial ----
    u16* ncp = numCp + (size_t)blockIdx.x * (B * D);
#pragma unroll
    for (int dt = 0; dt < 16; ++dt)
#pragma unroll
        for (int r = 0; r < 4; ++r)
            ncp[(b0 + 4 * q + r) * D + 16 * dt + l] = f2bf(acc[dt][r]);

    // ---- numK mini-PV: keys rows m0..m0+15, slot2(m) = 2*(m&7)+(m>>3); A zero-padded ----
    __syncthreads();   // all waves done reading sETu/sPu
    {
        int rp = t >> 5;   // 0..7
        uint4 ka = *(const uint4*)(keb + (size_t)(m0 + rp) * D + sp * 8);
        uint4 kb = *(const uint4*)(keb + (size_t)(m0 + rp + 8) * D + sp * 8);
#pragma unroll
        for (int j = 0; j < 8; ++j) {
            unsigned a0 = (((unsigned*)&ka)[j >> 1] >> ((j & 1) * 16)) & 0xFFFFu;
            unsigned a1 = (((unsigned*)&kb)[j >> 1] >> ((j & 1) * 16)) & 0xFFFFu;
            int d = 8 * sp + j;
            int sl = 2 * rp;   // slots 2rp, 2rp+1
            int off = (d >> 2) * 136 + (sl >> 3) * 32 + (d & 3) * 8 + (sl & 7);
            *(unsigned*)&sETu[0][off] = a0 | (a1 << 16);
        }
        // weights into sP (slots 0..15 = flash weights, 16..31 = 0)
#pragma unroll
        for (int i = 0; i < 4; ++i) {
            int m = 4 * i + y;
            int slot = 2 * (m & 7) + (m >> 3);
            sPu[bb * STR_P + slot] = f2bf(sw[m][bb]);
        }
        *(uint2*)&sPu[bb * STR_P + 16 + 4 * y] = make_uint2(0u, 0u);
    }
    __syncthreads();
    fx4 acc2[16];
#pragma unroll
    for (int dt = 0; dt < 16; ++dt) acc2[dt] = zero4;
    {
        bf16x8 pa2 = *(const bf16x8*)&sPu[(b0 + l) * STR_P + 8 * q];
#pragma unroll
        for (int dt = 0; dt < 16; ++dt) {
            bf16x8 eb2 = *(const bf16x8*)&sETu[0][offL + dt * 544 + q * 32];
            acc2[dt] = __builtin_amdgcn_mfma_f32_16x16x32_bf16(pa2, eb2, acc2[dt], 0, 0, 0);
        }
    }
    u16* nkp = numKp + (size_t)blockIdx.x * (B * D);
#pragma unroll
    for (int dt = 0; dt < 16; ++dt)
#pragma unroll
        for (int r = 0; r < 4; ++r)
            nkp[(b0 + 4 * q + r) * D + 16 * dt + l] = f2bf(acc2[dt][r]);
}

// ---- k_comb2: fused global stats + 500-way partial reduce -> o_k, comb ----
// 512 blocks: (b x 8 d-chunks). Stats computed redundantly per block (L2-hot, ~4 KB).
__global__ __launch_bounds__(256) void k_comb2(const u16* __restrict__ numCp,
                                               const u16* __restrict__ numKp,
                                               const float* __restrict__ mLp,
                                               const float* __restrict__ denLp,
                                               float* __restrict__ o_k,
                                               float* __restrict__ comb) {
    __shared__ float sscale[NBLK];
    __shared__ float red[256];
    __shared__ float ro[8][32], rc[8][32];
    __shared__ float srden;
    int bid = blockIdx.x;
    int b = bid >> 3, d0 = (bid & 7) * 32;
    int t = threadIdx.x;
    // pass 1: global max over 500 block-maxes
    float mx = -INFINITY;
    for (int blk = t; blk < NBLK; blk += 256) mx = fmaxf(mx, mLp[blk * B + b]);
    red[t] = mx;
    __syncthreads();
    for (int s = 128; s > 0; s >>= 1) {
        if (t < s) red[t] = fmaxf(red[t], red[t + s]);
        __syncthreads();
    }
    float Mg = red[0];
    __syncthreads();
    // pass 2: scales + denominator
    float ds = 0.f;
    for (int blk = t; blk < NBLK; blk += 256) {
        float sc = __expf(mLp[blk * B + b] - Mg);
        sscale[blk] = sc;
        ds += sc * denLp[blk * B + b];
    }
    red[t] = ds;
    __syncthreads();
    for (int s = 128; s > 0; s >>= 1) {
        if (t < s) red[t] += red[t + s];
        __syncthreads();
    }
    if (t == 0) srden = 1.f / red[0];
    __syncthreads();
    // main: 8 lane-stripes over the 500 partials
    int dd = t & 31, s = t >> 5;
    float ao = 0.f, ac = 0.f;
    for (int blk = s; blk < NBLK; blk += 8) {
        float sc = sscale[blk];
        size_t i = (size_t)blk * (B * D) + (size_t)b * D + d0 + dd;
        ao += sc * bf2f(numKp[i]);
        ac += sc * bf2f(numCp[i]);
    }
    ro[s][dd] = ao;
    rc[s][dd] = ac;
    __syncthreads();
    if (t < 32) {
        float so = 0.f, sc2 = 0.f;
#pragma unroll
        for (int k = 0; k < 8; ++k) { so += ro[k][t]; sc2 += rc[k][t]; }
        float rd = srden;
        o_k[b * D + d0 + t] = so * rd;
        comb[b * D + d0 + t] = sc2 * rd;
    }
}

// ==================== launcher ====================

extern "C" void kernel_launch(void* const* d_in, const int* in_sizes, int n_in,
                              void* d_out, int out_size, void* d_ws, size_t ws_size,
                              hipStream_t stream) {
    const int*   keys    = (const int*)d_in[0];
    const int*   entries = (const int*)d_in[1];
    const float* query   = (const float*)d_in[2];
    const float* wordemb = (const float*)d_in[3];
    const float* qproj_w = (const float*)d_in[4];
    const float* qproj_b = (const float*)d_in[5];

    float* out  = (float*)d_out;
    float* o_k  = out;
    float* lg   = out + B * D;
    float* comb = out + B * D + B * M;

    char* wsb = (char*)d_ws;
    u16*   keb   = (u16*)wsb;                      //  4,096,000 B
    u16*   qbf   = (u16*)(wsb + 4096000);          //     32,768 B
    u16*   vqb   = (u16*)(wsb + 4128768);          //     32,768 B
    u16*   numCp = (u16*)(wsb + 4161536);          // 16,384,000 B
    u16*   numKp = (u16*)(wsb + 20545536);         // 16,384,000 B
    float* mLp   = (float*)(wsb + 36929536);       //    128,000 B
    float* denLp = (float*)(wsb + 37057536);       //    128,000 B  (end 37,185,536)

    k_prep2<<<1072, 256, 0, stream>>>(keys, wordemb, query, qproj_w, qproj_b,
                                      qbf, keb, vqb);
    k_heavy_f<<<NBLK, 256, 0, stream>>>(entries, wordemb, vqb, qbf, keb, lg,
                                        numCp, numKp, mLp, denLp);
    k_comb2<<<512, 256, 0, stream>>>(numCp, numKp, mLp, denLp, o_k, comb);
}

// Round 12
// 175.782 us; speedup vs baseline: 1.0055x; 1.0055x over previous
//
#include <hip/hip_runtime.h>
#include <math.h>

#define B 64
#define D 256
#define M 8000
#define N 32
#define LG_LD 8000
#define EPB 16          // entries per block (flash k_heavy)
#define NBLK (M / EPB)  // 500

typedef unsigned short u16;
typedef __bf16 bf16x8 __attribute__((ext_vector_type(8)));
typedef float fx4 __attribute__((ext_vector_type(4)));

#define STR_E  264   // u16 stride of sE rows (n-major)
#define STR_P  40    // u16 stride of sP rows (b-major)
// sET interleaved layout: u16 idx of (d, slot) = (d>>2)*136 + (slot>>3)*32 + (d&3)*8 + (slot&7)
// entry-phase slot = sigma(n) = 4*(n&7) + (n>>3); key-phase slot2(m) = 2*(m&7) + (m>>3)

static __device__ __forceinline__ u16 f2bf(float x) {
    unsigned int u = __float_as_uint(x);
    u += 0x7FFFu + ((u >> 16) & 1u);
    return (u16)(u >> 16);
}
static __device__ __forceinline__ float bf2f(u16 h) {
    return __uint_as_float(((unsigned)h) << 16);
}
static __device__ __forceinline__ uint4 pack8(float4 va, float4 vb, float msk) {
    unsigned p0 = (unsigned)f2bf(va.x * msk) | ((unsigned)f2bf(va.y * msk) << 16);
    unsigned p1 = (unsigned)f2bf(va.z * msk) | ((unsigned)f2bf(va.w * msk) << 16);
    unsigned p2 = (unsigned)f2bf(vb.x * msk) | ((unsigned)f2bf(vb.y * msk) << 16);
    unsigned p3 = (unsigned)f2bf(vb.z * msk) | ((unsigned)f2bf(vb.w * msk) << 16);
    return make_uint4(p0, p1, p2, p3);
}

// ---- k_prep2: keb gather (0..999) + qbf conv (1000..1007) + vq proj (1008..1071)
__global__ __launch_bounds__(256) void k_prep2(const int* __restrict__ keys,
                                               const float* __restrict__ emb,
                                               const float* __restrict__ q,
                                               const float* __restrict__ W,
                                               const float* __restrict__ bias,
                                               u16* __restrict__ qbf,
                                               u16* __restrict__ keb,
                                               u16* __restrict__ vqb) {
    __shared__ float qs[D];
    int t = threadIdx.x, bid = blockIdx.x;
    if (bid < 1000) {
        int c = bid * 256 + t;   // 8000*32 chunks of 8 elems
        int j = c >> 5, sp = c & 31;
        int id = keys[j];
        const float* rp = emb + (size_t)id * D + sp * 8;
        float4 v0 = *(const float4*)rp;
        float4 v1 = *(const float4*)(rp + 4);
        float msk = (id != 0) ? 1.f : 0.f;
        uint4 pk = pack8(v0, v1, msk);
        *(uint4*)(keb + (size_t)j * D + sp * 8) = pk;
    } else if (bid < 1008) {
        size_t idx = (size_t)(bid - 1000) * 2048 + (size_t)t * 8;
        float4 v0 = *(const float4*)(q + idx);
        float4 v1 = *(const float4*)(q + idx + 4);
        uint4 pk = pack8(v0, v1, 1.f);
        *(uint4*)(qbf + idx) = pk;
    } else {
        int b = bid - 1008;
        qs[t] = q[b * D + t];
        __syncthreads();
        const float* wr = W + t * D;
        float acc = bias[t];
#pragma unroll 8
        for (int k = 0; k < D; k += 4) {
            float4 w4 = *(const float4*)(wr + k);
            acc += qs[k] * w4.x + qs[k + 1] * w4.y + qs[k + 2] * w4.z + qs[k + 3] * w4.w;
        }
        vqb[b * D + t] = f2bf(acc);
    }
}

// ---- k_heavy_f: fused logits + flash stats + per-entry value attention + numK mini-PV.
//      fp32 gather straight from wordemb; bf16 convert+mask fused into staging.
//      Entry loop: proven dbuf structure, 1 barrier/entry, unroll 2 (I-cache-resident;
//      full unroll of the 16-iter body regressed 2x in round 11 via L1I thrash).
__global__ __launch_bounds__(256, 2) void k_heavy_f(const int* __restrict__ entries,
                                                    const float* __restrict__ emb,
                                                    const u16* __restrict__ vqb,
                                                    const u16* __restrict__ qbf,
                                                    const u16* __restrict__ keb,
                                                    float* __restrict__ lg,
                                                    u16* __restrict__ numCp,
                                                    u16* __restrict__ numKp,
                                                    float* __restrict__ mLp,
                                                    float* __restrict__ denLp) {
    __shared__ __align__(16) u16 sEu[2][N * STR_E];   // 33,792 B
    __shared__ __align__(16) u16 sETu[2][64 * 136];   // 34,816 B
    __shared__ __align__(16) u16 sPu[B * STR_P];      //  5,120 B
    __shared__ float sw[EPB][B];                      //  4,096 B

    int t = threadIdx.x;
    int lane = t & 63, l = lane & 15, q = lane >> 4, w = t >> 6;
    int b0 = 16 * w;
    int sp = t & 31, n0 = t >> 5;
    int m0 = blockIdx.x * EPB;
    int bb = t & 63, y = t >> 6;

    // ---- earliest: ids(e0) + fp32 gather(e0) — flies underneath the fused logits ----
    int idc[4], idn[4];
    float4 pfF[8];   // 4 rows x 2 float4 (32 B per row-chunk)
#pragma unroll
    for (int i = 0; i < 4; ++i) idc[i] = entries[m0 * N + n0 + 8 * i];
#pragma unroll
    for (int i = 0; i < 4; ++i) {
        const float* rp = emb + (size_t)idc[i] * D + sp * 8;
        pfF[2 * i]     = *(const float4*)rp;
        pfF[2 * i + 1] = *(const float4*)(rp + 4);
    }

    // ---- fused logits: aL[r] = lg[b0+4q+r][m0+l]  (16 m x 64 b tile) ----
    fx4 zero4 = {0.f, 0.f, 0.f, 0.f};
    fx4 aL = zero4;
#pragma unroll
    for (int s = 0; s < 8; ++s) {
        bf16x8 a  = *(const bf16x8*)(qbf + (size_t)(b0 + l) * D + 32 * s + 8 * q);
        bf16x8 bq = *(const bf16x8*)(keb + (size_t)(m0 + l) * D + 32 * s + 8 * q);
        aL = __builtin_amdgcn_mfma_f32_16x16x32_bf16(a, bq, aL, 0, 0, 0);
    }
#pragma unroll
    for (int r = 0; r < 4; ++r)
        lg[(size_t)(b0 + 4 * q + r) * LG_LD + m0 + l] = aL[r];

    // ---- flash stats via 16-lane shuffles: mL[b], weights sw[m][b], den[b] ----
#pragma unroll
    for (int r = 0; r < 4; ++r) {
        float m_ = aL[r];
        m_ = fmaxf(m_, __shfl_xor(m_, 1));
        m_ = fmaxf(m_, __shfl_xor(m_, 2));
        m_ = fmaxf(m_, __shfl_xor(m_, 4));
        m_ = fmaxf(m_, __shfl_xor(m_, 8));
        float wv = __expf(aL[r] - m_);
        sw[l][b0 + 4 * q + r] = wv;     // entry m0+l, batch b0+4q+r (wave-private columns)
        float d_ = wv;
        d_ += __shfl_xor(d_, 1);
        d_ += __shfl_xor(d_, 2);
        d_ += __shfl_xor(d_, 4);
        d_ += __shfl_xor(d_, 8);
        if (l == 0) {
            mLp[blockIdx.x * B + b0 + 4 * q + r] = m_;
            denLp[blockIdx.x * B + b0 + 4 * q + r] = d_;
        }
    }

    // persistent vq B-fragments
    bf16x8 vqf[8];
#pragma unroll
    for (int s = 0; s < 8; ++s)
        vqf[s] = *(const bf16x8*)(vqb + (b0 + l) * D + 32 * s + 8 * q);

    fx4 acc[16];
#pragma unroll
    for (int dt = 0; dt < 16; ++dt) acc[dt] = zero4;

    // ---- gather pipeline prologue: buf0 <- e0 (convert+mask); pfF <- e1; idn <- ids(e2) ----
    {
        uint4 pk[4];
#pragma unroll
        for (int i = 0; i < 4; ++i) {
            float msk = (idc[i] != 0) ? 1.f : 0.f;
            pk[i] = pack8(pfF[2 * i], pfF[2 * i + 1], msk);
            *(uint4*)&sEu[0][(n0 + 8 * i) * STR_E + sp * 8] = pk[i];
        }
#pragma unroll
        for (int j = 0; j < 8; ++j) {
            unsigned a0 = (((unsigned*)&pk[0])[j >> 1] >> ((j & 1) * 16)) & 0xFFFFu;
            unsigned a1 = (((unsigned*)&pk[1])[j >> 1] >> ((j & 1) * 16)) & 0xFFFFu;
            unsigned a2 = (((unsigned*)&pk[2])[j >> 1] >> ((j & 1) * 16)) & 0xFFFFu;
            unsigned a3 = (((unsigned*)&pk[3])[j >> 1] >> ((j & 1) * 16)) & 0xFFFFu;
            uint2 pr = make_uint2(a0 | (a1 << 16), a2 | (a3 << 16));
            int off = (2 * sp + (j >> 2)) * 136 + (n0 >> 1) * 32 + (j & 3) * 8 + (n0 & 1) * 4;
            *(uint2*)&sETu[0][off] = pr;
        }
    }
#pragma unroll
    for (int i = 0; i < 4; ++i) idc[i] = entries[(m0 + 1) * N + n0 + 8 * i];
#pragma unroll
    for (int i = 0; i < 4; ++i) {
        const float* rp = emb + (size_t)idc[i] * D + sp * 8;
        pfF[2 * i]     = *(const float4*)rp;
        pfF[2 * i + 1] = *(const float4*)(rp + 4);
    }
#pragma unroll
    for (int i = 0; i < 4; ++i) idn[i] = entries[(m0 + 2) * N + n0 + 8 * i];

    int offL = (l >> 2) * 136 + (l & 3) * 8;

    // ---- entry loop: 1 barrier per entry; compute e from buf[e&1] ----
#pragma unroll 2
    for (int e = 0; e < EPB; ++e) {
        __syncthreads();   // buf[e&1] staged; prev reads of buf[(e+1)&1] done; drains gather(e+1)
        int nxt = (e + 1) & 1;
        if (e < EPB - 1) {
            // (a) stage entry e+1 (held in pfF): convert+mask, write sE (b128) + sET (b64)
            uint4 pk[4];
#pragma unroll
            for (int i = 0; i < 4; ++i) {
                float msk = (idc[i] != 0) ? 1.f : 0.f;
                pk[i] = pack8(pfF[2 * i], pfF[2 * i + 1], msk);
                *(uint4*)&sEu[nxt][(n0 + 8 * i) * STR_E + sp * 8] = pk[i];
            }
#pragma unroll
            for (int j = 0; j < 8; ++j) {
                unsigned a0 = (((unsigned*)&pk[0])[j >> 1] >> ((j & 1) * 16)) & 0xFFFFu;
                unsigned a1 = (((unsigned*)&pk[1])[j >> 1] >> ((j & 1) * 16)) & 0xFFFFu;
                unsigned a2 = (((unsigned*)&pk[2])[j >> 1] >> ((j & 1) * 16)) & 0xFFFFu;
                unsigned a3 = (((unsigned*)&pk[3])[j >> 1] >> ((j & 1) * 16)) & 0xFFFFu;
                uint2 pr = make_uint2(a0 | (a1 << 16), a2 | (a3 << 16));
                int off = (2 * sp + (j >> 2)) * 136 + (n0 >> 1) * 32 + (j & 3) * 8 + (n0 & 1) * 4;
                *(uint2*)&sETu[nxt][off] = pr;
            }
            // (b) issue fp32 gather entry e+2 (stays in flight through this entry's compute)
            if (e < EPB - 2) {
#pragma unroll
                for (int i = 0; i < 4; ++i) {
                    const float* rp = emb + (size_t)idn[i] * D + sp * 8;
                    pfF[2 * i]     = *(const float4*)rp;
                    pfF[2 * i + 1] = *(const float4*)(rp + 4);
                }
#pragma unroll
                for (int i = 0; i < 4; ++i) idc[i] = idn[i];
                if (e < EPB - 3) {
#pragma unroll
                    for (int i = 0; i < 4; ++i) idn[i] = entries[(m0 + e + 3) * N + n0 + 8 * i];
                }
            }
        }
        // (c) compute entry e from buf[cur]
        int cur = e & 1;
        fx4 accS[2];
        accS[0] = zero4; accS[1] = zero4;
#pragma unroll
        for (int T = 0; T < 2; ++T)
#pragma unroll
            for (int s = 0; s < 8; ++s) {
                bf16x8 ea = *(const bf16x8*)&sEu[cur][(16 * T + l) * STR_E + 32 * s + 8 * q];
                accS[T] = __builtin_amdgcn_mfma_f32_16x16x32_bf16(ea, vqf[s], accS[T], 0, 0, 0);
            }
        float swb = sw[e][b0 + l];
        float mx = -INFINITY;
#pragma unroll
        for (int T = 0; T < 2; ++T)
#pragma unroll
            for (int r = 0; r < 4; ++r) mx = fmaxf(mx, accS[T][r]);
        mx = fmaxf(mx, __shfl_xor(mx, 16));
        mx = fmaxf(mx, __shfl_xor(mx, 32));
        float pe[2][4], sum = 0.f;
#pragma unroll
        for (int T = 0; T < 2; ++T)
#pragma unroll
            for (int r = 0; r < 4; ++r) {
                pe[T][r] = __expf(accS[T][r] - mx);
                sum += pe[T][r];
            }
        sum += __shfl_xor(sum, 16);
        sum += __shfl_xor(sum, 32);
        float sc = swb / sum;
#pragma unroll
        for (int T = 0; T < 2; ++T)
#pragma unroll
            for (int r = 0; r < 4; ++r) {
                int nn = 16 * T + 4 * q + r;
                int slot = 4 * (nn & 7) + (nn >> 3);
                sPu[(b0 + l) * STR_P + slot] = f2bf(pe[T][r] * sc);
            }
        bf16x8 pa = *(const bf16x8*)&sPu[(b0 + l) * STR_P + 8 * q];
#pragma unroll
        for (int dt = 0; dt < 16; ++dt) {
            bf16x8 eb = *(const bf16x8*)&sETu[cur][offL + dt * 544 + q * 32];
            acc[dt] = __builtin_amdgcn_mfma_f32_16x16x32_bf16(pa, eb, acc[dt], 0, 0, 0);
        }
    }

    // ---- store numC partial ----
    u16* ncp = numCp + (size_t)blockIdx.x * (B * D);
#pragma unroll
    for (int dt = 0; dt < 16; ++dt)
#pragma unroll
        for (int r = 0; r < 4; ++r)
            ncp[(b0 + 4 * q + r) * D + 16 * dt + l] = f2bf(acc[dt][r]);

    // ---- numK mini-PV: keys rows m0..m0+15, slot2(m) = 2*(m&7)+(m>>3); A zero-padded ----
    __syncthreads();   // all waves done reading sETu/sPu
    {
        int rp = t >> 5;   // 0..7
        uint4 ka = *(const uint4*)(keb + (size_t)(m0 + rp) * D + sp * 8);
        uint4 kb = *(const uint4*)(keb + (size_t)(m0 + rp + 8) * D + sp * 8);
#pragma unroll
        for (int j = 0; j < 8; ++j) {
            unsigned a0 = (((unsigned*)&ka)[j >> 1] >> ((j & 1) * 16)) & 0xFFFFu;
            unsigned a1 = (((unsigned*)&kb)[j >> 1] >> ((j & 1) * 16)) & 0xFFFFu;
            int d = 8 * sp + j;
            int sl = 2 * rp;   // slots 2rp, 2rp+1
            int off = (d >> 2) * 136 + (sl >> 3) * 32 + (d & 3) * 8 + (sl & 7);
            *(unsigned*)&sETu[0][off] = a0 | (a1 << 16);
        }
        // weights into sP (slots 0..15 = flash weights, 16..31 = 0)
#pragma unroll
        for (int i = 0; i < 4; ++i) {
            int m = 4 * i + y;
            int slot = 2 * (m & 7) + (m >> 3);
            sPu[bb * STR_P + slot] = f2bf(sw[m][bb]);
        }
        *(uint2*)&sPu[bb * STR_P + 16 + 4 * y] = make_uint2(0u, 0u);
    }
    __syncthreads();
    fx4 acc2[16];
#pragma unroll
    for (int dt = 0; dt < 16; ++dt) acc2[dt] = zero4;
    {
        bf16x8 pa2 = *(const bf16x8*)&sPu[(b0 + l) * STR_P + 8 * q];
#pragma unroll
        for (int dt = 0; dt < 16; ++dt) {
            bf16x8 eb2 = *(const bf16x8*)&sETu[0][offL + dt * 544 + q * 32];
            acc2[dt] = __builtin_amdgcn_mfma_f32_16x16x32_bf16(pa2, eb2, acc2[dt], 0, 0, 0);
        }
    }
    u16* nkp = numKp + (size_t)blockIdx.x * (B * D);
#pragma unroll
    for (int dt = 0; dt < 16; ++dt)
#pragma unroll
        for (int r = 0; r < 4; ++r)
            nkp[(b0 + 4 * q + r) * D + 16 * dt + l] = f2bf(acc2[dt][r]);
}

// ---- k_comb2: fused global stats + 500-way partial reduce -> o_k, comb ----
// 512 blocks: (b x 8 d-chunks). Stats computed redundantly per block (L2-hot, ~4 KB).
__global__ __launch_bounds__(256) void k_comb2(const u16* __restrict__ numCp,
                                               const u16* __restrict__ numKp,
                                               const float* __restrict__ mLp,
                                               const float* __restrict__ denLp,
                                               float* __restrict__ o_k,
                                               float* __restrict__ comb) {
    __shared__ float sscale[NBLK];
    __shared__ float red[256];
    __shared__ float ro[8][32], rc[8][32];
    __shared__ float srden;
    int bid = blockIdx.x;
    int b = bid >> 3, d0 = (bid & 7) * 32;
    int t = threadIdx.x;
    // pass 1: global max over 500 block-maxes
    float mx = -INFINITY;
    for (int blk = t; blk < NBLK; blk += 256) mx = fmaxf(mx, mLp[blk * B + b]);
    red[t] = mx;
    __syncthreads();
    for (int s = 128; s > 0; s >>= 1) {
        if (t < s) red[t] = fmaxf(red[t], red[t + s]);
        __syncthreads();
    }
    float Mg = red[0];
    __syncthreads();
    // pass 2: scales + denominator
    float ds = 0.f;
    for (int blk = t; blk < NBLK; blk += 256) {
        float sc = __expf(mLp[blk * B + b] - Mg);
        sscale[blk] = sc;
        ds += sc * denLp[blk * B + b];
    }
    red[t] = ds;
    __syncthreads();
    for (int s = 128; s > 0; s >>= 1) {
        if (t < s) red[t] += red[t + s];
        __syncthreads();
    }
    if (t == 0) srden = 1.f / red[0];
    __syncthreads();
    // main: 8 lane-stripes over the 500 partials
    int dd = t & 31, s = t >> 5;
    float ao = 0.f, ac = 0.f;
    for (int blk = s; blk < NBLK; blk += 8) {
        float sc = sscale[blk];
        size_t i = (size_t)blk * (B * D) + (size_t)b * D + d0 + dd;
        ao += sc * bf2f(numKp[i]);
        ac += sc * bf2f(numCp[i]);
    }
    ro[s][dd] = ao;
    rc[s][dd] = ac;
    __syncthreads();
    if (t < 32) {
        float so = 0.f, sc2 = 0.f;
#pragma unroll
        for (int k = 0; k < 8; ++k) { so += ro[k][t]; sc2 += rc[k][t]; }
        float rd = srden;
        o_k[b * D + d0 + t] = so * rd;
        comb[b * D + d0 + t] = sc2 * rd;
    }
}

// ==================== launcher ====================

extern "C" void kernel_launch(void* const* d_in, const int* in_sizes, int n_in,
                              void* d_out, int out_size, void* d_ws, size_t ws_size,
                              hipStream_t stream) {
    const int*   keys    = (const int*)d_in[0];
    const int*   entries = (const int*)d_in[1];
    const float* query   = (const float*)d_in[2];
    const float* wordemb = (const float*)d_in[3];
    const float* qproj_w = (const float*)d_in[4];
    const float* qproj_b = (const float*)d_in[5];

    float* out  = (float*)d_out;
    float* o_k  = out;
    float* lg   = out + B * D;
    float* comb = out + B * D + B * M;

    char* wsb = (char*)d_ws;
    u16*   keb   = (u16*)wsb;                      //  4,096,000 B
    u16*   qbf   = (u16*)(wsb + 4096000);          //     32,768 B
    u16*   vqb   = (u16*)(wsb + 4128768);          //     32,768 B
    u16*   numCp = (u16*)(wsb + 4161536);          // 16,384,000 B
    u16*   numKp = (u16*)(wsb + 20545536);         // 16,384,000 B
    float* mLp   = (float*)(wsb + 36929536);       //    128,000 B
    float* denLp = (float*)(wsb + 37057536);       //    128,000 B  (end 37,185,536)

    k_prep2<<<1072, 256, 0, stream>>>(keys, wordemb, query, qproj_w, qproj_b,
                                      qbf, keb, vqb);
    k_heavy_f<<<NBLK, 256, 0, stream>>>(entries, wordemb, vqb, qbf, keb, lg,
                                        numCp, numKp, mLp, denLp);
    k_comb2<<<512, 256, 0, stream>>>(numCp, numKp, mLp, denLp, o_k, comb);
}